// Round 7
// baseline (8141.310 us; speedup 1.0000x reference)
//
#include <hip/hip_runtime.h>
#include <hip/hip_bf16.h>
#include <stdint.h>

#define EPS 1e-5f

typedef int v4i __attribute__((ext_vector_type(4)));
typedef int v16i __attribute__((ext_vector_type(16)));
typedef const __attribute__((address_space(1))) void g_void;
typedef __attribute__((address_space(3))) void l_void;

// ---------------- block reductions ----------------
__device__ inline float block_max_nw(float v, int nw) {
    __shared__ float s[8];
#pragma unroll
    for (int o = 32; o; o >>= 1) v = fmaxf(v, __shfl_xor(v, o, 64));
    if ((threadIdx.x & 63) == 0) s[threadIdx.x >> 6] = v;
    __syncthreads();
    float m = s[0];
    for (int i = 1; i < nw; ++i) m = fmaxf(m, s[i]);
    return m;
}

__device__ inline float block_sum64x4(float v) {
    __shared__ float s[4];
#pragma unroll
    for (int o = 32; o; o >>= 1) v += __shfl_xor(v, o, 64);
    if ((threadIdx.x & 63) == 0) s[threadIdx.x >> 6] = v;
    __syncthreads();
    return s[0] + s[1] + s[2] + s[3];
}

// ---------------- |w| sums for BOTH weights in one launch ----------------
__global__ __launch_bounds__(256) void abs_sum_part_k(const float4* __restrict__ w0,
                                                      const float4* __restrict__ w1,
                                                      float* __restrict__ part) {
    const int half = blockIdx.x >> 10;            // 0 or 1
    const float4* w = half ? w1 : w0;
    float s = 0.0f;
    for (int i = (blockIdx.x & 1023) * 256 + threadIdx.x; i < 786432; i += 1024 * 256) {
        float4 v = w[i];
        s += fabsf(v.x) + fabsf(v.y) + fabsf(v.z) + fabsf(v.w);
    }
    s = block_sum64x4(s);
    if (threadIdx.x == 0) part[blockIdx.x] = s;
}

// ---------------- |w| sum: stage 2 ----------
__global__ __launch_bounds__(256) void abs_sum_final_k(const float* __restrict__ parts,
                                                       float* __restrict__ sums) {
    const float* p = parts + blockIdx.x * 1024;
    const int t = threadIdx.x;
    float s = p[t] + p[t + 256] + p[t + 512] + p[t + 768];
    s = block_sum64x4(s);
    if (t == 0) sums[blockIdx.x] = s;
}

// ---------------- ternary weight quantization, BOTH weights one launch --------
__global__ __launch_bounds__(256) void wquant_k(const float4* __restrict__ w0,
                                                const float4* __restrict__ w1,
                                                char4* __restrict__ q0,
                                                char4* __restrict__ q1,
                                                const float* __restrict__ sums) {
    const int half = (blockIdx.x >= 3072) ? 1 : 0;
    const float4* w = half ? w1 : w0;
    char4* q = half ? q1 : q0;
    const float mean = fmaxf(sums[half] * (1.0f / 3145728.0f), EPS);
    const float scale = 1.0f / mean;
    const int i = (blockIdx.x - half * 3072) * 256 + threadIdx.x;
    float4 v = w[i];
    char4 c;
    c.x = (signed char)(int)fmaxf(fminf(rintf(v.x * scale), 1.0f), -1.0f);
    c.y = (signed char)(int)fmaxf(fminf(rintf(v.y * scale), 1.0f), -1.0f);
    c.z = (signed char)(int)fmaxf(fminf(rintf(v.z * scale), 1.0f), -1.0f);
    c.w = (signed char)(int)fmaxf(fminf(rintf(v.w * scale), 1.0f), -1.0f);
    q[i] = c;
}

// ---------------- per-token int8 quantization of x (rows of 1024 fp32) ----------
// R0-R4 proven block-per-row form (wave-per-row variant measured ~+20us slower).
__global__ __launch_bounds__(256) void aquant_k(const float4* __restrict__ x,
                                                char4* __restrict__ q,
                                                float* __restrict__ deq) {
    const int row = blockIdx.x, t = threadIdx.x;
    const float4 v = x[(size_t)row * 256 + t];
    float m = fmaxf(fmaxf(fabsf(v.x), fabsf(v.y)), fmaxf(fabsf(v.z), fabsf(v.w)));
    m = block_max_nw(m, 4);
    const float mc = fmaxf(m, EPS);
    const float sc = 127.0f / mc;
    char4 c;
    c.x = (signed char)(int)fmaxf(fminf(rintf(v.x * sc), 127.0f), -128.0f);
    c.y = (signed char)(int)fmaxf(fminf(rintf(v.y * sc), 127.0f), -128.0f);
    c.z = (signed char)(int)fmaxf(fminf(rintf(v.z * sc), 127.0f), -128.0f);
    c.w = (signed char)(int)fmaxf(fminf(rintf(v.w * sc), 127.0f), -128.0f);
    q[(size_t)row * 256 + t] = c;
    if (t == 0) deq[row] = mc / 127.0f;
}

// ---------------- per-token quant of bf16 hidden rows (3072), IN PLACE ----------
__global__ __launch_bounds__(384) void hquant_k(unsigned short* __restrict__ hid,
                                                float* __restrict__ deq) {
    const size_t row = blockIdx.x;
    const int t = threadIdx.x;
    unsigned short* rp = hid + row * 3072;
    const uint4 u = ((const uint4*)rp)[t];
    float v[8];
    {
        uint32_t uu[4] = {u.x, u.y, u.z, u.w};
#pragma unroll
        for (int i = 0; i < 4; ++i) {
            uint32_t lo = uu[i] << 16, hi = uu[i] & 0xFFFF0000u;
            v[2 * i]     = __uint_as_float(lo);
            v[2 * i + 1] = __uint_as_float(hi);
        }
    }
    float m = 0.0f;
#pragma unroll
    for (int i = 0; i < 8; ++i) m = fmaxf(m, fabsf(v[i]));
    m = block_max_nw(m, 6);   // contains __syncthreads(): loads done before stores
    const float mc = fmaxf(m, EPS);
    const float sc = 127.0f / mc;
    uint32_t p0 = 0, p1 = 0;
#pragma unroll
    for (int i = 0; i < 4; ++i) {
        int c = (int)fminf(rintf(v[i] * sc), 127.0f);          // v >= 0 (relu^2)
        p0 |= (uint32_t)(c & 255) << (8 * i);
    }
#pragma unroll
    for (int i = 0; i < 4; ++i) {
        int c = (int)fminf(rintf(v[4 + i] * sc), 127.0f);
        p1 |= (uint32_t)(c & 255) << (8 * i);
    }
    uint2 pk; pk.x = p0; pk.y = p1;
    ((uint2*)rp)[t] = pk;
    if (t == 0) deq[row] = mc / 127.0f;
}

// ---------------- int8 GEMM: C[m][n] = sum_k A[m][k]*B[n][k] ----------------
// 128(m)x256(n), 256 thr = 4 waves (2x2), wave tile 64x128 as 2x4 of
// v_mfma_i32_32x32x32_i8, BK=64.
// NEW: B (ternary weights, 3MB, L2-resident per XCD) is loaded DIRECTLY from
// global into register fragments (no LDS staging): per instr 32 consecutive
// rows x 32B contiguous (ks pair shares a 64B line -> no over-fetch; wave
// pairs dedup via L1). Removes 2/3 of LDS-pipe traffic (R6 accounting: B was
// 16KB of 24KB staging + 32 of 48 b128 reads/block-iter). B is register
// double-buffered (bfc/bfn): loads for iter tt+1 issue at top of tt, a full
// iter (~1500cyc >> 200cyc L2) before use; compiler's pre-MFMA vmcnt is the
// counted wait. A: ring-3 LDS, 3 x 8KB = 24KB -> 6 blocks/CU; stage tt+2 at
// top of tt; end-of-iter vmcnt(18) (= B(tt) 8 + A(tt+2) 2 + B(tt+1) 8 newer
// than A(tt+1)) is provably already satisfied (pre-MFMA wait is tighter) ->
// zero drain cost, never waits on the just-issued tile. One barrier/iter
// publishes A(tt+1). K templated + full unroll: zero in-loop VALU (R5).
// LDS rows 64B, 16B chunks XOR-swizzled by (row>>1)&3 folded into staging
// lanes' GLOBAL addresses. XCD map: blk&7.
template <int K, int NTILES, bool RELU2, typename OutT>
__global__ __launch_bounds__(256, 6) void gemm_i8(
    const int8_t* __restrict__ A, int lda,        // row pitch in bytes
    const int8_t* __restrict__ B, int ldb,
    OutT* __restrict__ O, int ldo,                // pitch in elements
    const float* __restrict__ rowDeq,
    const float* __restrict__ sumPtr,
    const float* __restrict__ bias) {
    constexpr int NT = K >> 6;                    // K-tiles of 64 (NT >= 2)
    __shared__ __align__(16) char lds[3][8192];   // A ring-3: 128 rows x 64 B each
    const int t = threadIdx.x;
    const int lane = t & 63;
    const int w = t >> 6;                         // wave 0..3
    const int xcd = blockIdx.x & 7;
    const int sb = blockIdx.x >> 3;
    const int bm = xcd + 8 * (sb / NTILES);
    const int bn = sb % NTILES;
    const long m0 = (long)bm * 128;
    const long n0 = (long)bn * 256;
    const long ldbL = (long)ldb;

    v16i acc[2][4];
#pragma unroll
    for (int i = 0; i < 2; ++i)
#pragma unroll
        for (int j = 0; j < 4; ++j) acc[i][j] = (v16i)(0);

    const int mloc = (w >> 1) * 64;
    const int nloc = (w & 1) * 128;
    const int r32 = lane & 31;
    const int h = lane >> 5;

    // ---- A staging bases (loop-invariant): 2 gload_lds per wave per tile ----
    const int srow = lane >> 2;
    const int scS = ((lane & 3) ^ ((lane >> 3) & 3)) * 16;  // pre-swizzled chunk
    const int8_t* paS0 = A + (m0 + w * 32 + srow) * (long)lda + scS;
    const int8_t* paS1 = paS0 + 16 * (long)lda;

    // ---- A fragment-read bases (loop-invariant): chunk (2ks+h)^((r>>1)&3) ----
    const int swz = (r32 >> 1) & 3;
    const char* rdA0 = &lds[0][0] + (mloc + r32) * 64 + ((h ^ swz) * 16);
    const char* rdA1 = &lds[0][0] + (mloc + r32) * 64 + (((2 + h) ^ swz) * 16);

    // ---- B direct-load base (per-lane): row n0+nloc+nt*32+r32, 16B at
    //      k = tt*64 + ks*32 + h*16 ----
    const int8_t* pB = B + (n0 + nloc + r32) * ldbL + h * 16;

    auto STAGE_A = [&](int tt) {                  // tt compile-time after unroll
        char* buf = &lds[0][0] + (tt % 3) * 8192;
        const long ko = (long)tt << 6;
        __builtin_amdgcn_global_load_lds((g_void*)(paS0 + ko),
                                         (l_void*)(buf + w * 2048), 16, 0, 0);
        __builtin_amdgcn_global_load_lds((g_void*)(paS1 + ko),
                                         (l_void*)(buf + w * 2048 + 1024), 16, 0, 0);
    };

    v4i bfc[2][4], bfn[2][4];

    // prologue: A tiles 0,1 in flight; B(0) -> bfc; wait A(0) only
    STAGE_A(0);
    STAGE_A(1);
#pragma unroll
    for (int ks = 0; ks < 2; ++ks)
#pragma unroll
        for (int nt = 0; nt < 4; ++nt)
            bfc[ks][nt] = *(const v4i*)(pB + (long)(nt * 32) * ldbL + ks * 32);
    asm volatile("s_waitcnt vmcnt(10)" ::: "memory");   // A(0): 10 newer in queue
    __builtin_amdgcn_s_barrier();
    __builtin_amdgcn_sched_barrier(0);

#pragma unroll
    for (int tt = 0; tt < NT; ++tt) {
        const int bo = (tt % 3) * 8192;           // compile-time after unroll
        if (tt + 2 < NT) STAGE_A(tt + 2);         // ring slot freed at iter tt-1
        if (tt + 1 < NT) {                        // B prefetch for next iter
            const long ko1 = ((long)(tt + 1)) << 6;
#pragma unroll
            for (int ks = 0; ks < 2; ++ks)
#pragma unroll
                for (int nt = 0; nt < 4; ++nt)
                    bfn[ks][nt] = *(const v4i*)(pB + (long)(nt * 32) * ldbL + ko1 + ks * 32);
        }
        __builtin_amdgcn_sched_barrier(0);        // pin prefetch issue at top

        v4i af[2][2];
#pragma unroll
        for (int ks = 0; ks < 2; ++ks) {
            const char* rA = ks ? rdA1 : rdA0;
#pragma unroll
            for (int mt = 0; mt < 2; ++mt)
                af[ks][mt] = *(const v4i*)(rA + bo + mt * 2048);
        }
#pragma unroll
        for (int ks = 0; ks < 2; ++ks)
#pragma unroll
            for (int mt = 0; mt < 2; ++mt)
#pragma unroll
                for (int nt = 0; nt < 4; ++nt)
                    acc[mt][nt] = __builtin_amdgcn_mfma_i32_32x32x32_i8(
                        af[ks][mt], bfc[ks][nt], acc[mt][nt], 0, 0, 0);
        if (tt + 1 < NT) {
#pragma unroll
            for (int ks = 0; ks < 2; ++ks)
#pragma unroll
                for (int nt = 0; nt < 4; ++nt)
                    bfc[ks][nt] = bfn[ks][nt];    // SSA rename, free after unroll
            // publish A(tt+1): newer ops = B(tt) 8 [+ A(tt+2) 2] + B(tt+1) 8.
            // Already satisfied by the compiler's pre-MFMA bfc wait -> ~free.
            if (tt + 2 < NT) asm volatile("s_waitcnt vmcnt(18)" ::: "memory");
            else             asm volatile("s_waitcnt vmcnt(16)" ::: "memory");
            __builtin_amdgcn_s_barrier();
            __builtin_amdgcn_sched_barrier(0);
        }
    }

    // epilogue: C/D layout col = lane&31, row = (reg&3) + 8*(reg>>2) + 4*(lane>>5)
    const float wdeq = fmaxf(sumPtr[0] * (1.0f / 3145728.0f), EPS);
#pragma unroll
    for (int mt = 0; mt < 2; ++mt) {
#pragma unroll
        for (int g = 0; g < 4; ++g) {
#pragma unroll
            for (int rr = 0; rr < 4; ++rr) {
                const long row = m0 + mloc + mt * 32 + g * 8 + h * 4 + rr;
                const float rs = rowDeq[row] * wdeq;
#pragma unroll
                for (int nt = 0; nt < 4; ++nt) {
                    const long col = n0 + nloc + nt * 32 + r32;
                    float val = (float)acc[mt][nt][g * 4 + rr] * rs + bias[col];
                    if (RELU2) {
                        val = fmaxf(val, 0.0f);
                        val = val * val;
                    }
                    O[row * (long)ldo + col] = (OutT)val;
                }
            }
        }
    }
}

// ---------------- launch ----------------
extern "C" void kernel_launch(void* const* d_in, const int* in_sizes, int n_in,
                              void* d_out, int out_size, void* d_ws, size_t ws_size,
                              hipStream_t stream) {
    const float* x      = (const float*)d_in[0];   // [32768,1024]
    const float* up_w   = (const float*)d_in[1];   // [3072,1024]
    const float* up_b   = (const float*)d_in[2];   // [3072]
    const float* down_w = (const float*)d_in[3];   // [1024,3072]
    const float* down_b = (const float*)d_in[4];   // [1024]

    // ws: sums 256B | parts 8KB | qw_dn 3MB | deqh 128KB | hidden bf16 201MB
    char* ws = (char*)d_ws;
    float*  sums   = (float*)ws;
    float*  parts  = (float*)(ws + 256);
    int8_t* qw_dn  = (int8_t*)(ws + 256 + 8192);
    float*  deqh   = (float*)(ws + 256 + 8192 + 3145728);
    __hip_bfloat16* hidden = (__hip_bfloat16*)(ws + 256 + 8192 + 3145728 + 131072);

    // d_out head as phase-1 scratch (dead before GEMM2 writes)
    int8_t* qx    = (int8_t*)d_out;                      // 33.5MB
    int8_t* qw_up = qx + 33554432;                       // 3MB
    float*  deqx  = (float*)(qx + 33554432 + 3145728);   // 128KB

    abs_sum_part_k<<<2048, 256, 0, stream>>>((const float4*)up_w,
                                             (const float4*)down_w, parts);
    abs_sum_final_k<<<2, 256, 0, stream>>>(parts, sums);

    wquant_k<<<6144, 256, 0, stream>>>((const float4*)up_w, (const float4*)down_w,
                                       (char4*)qw_up, (char4*)qw_dn, sums);
    aquant_k<<<32768, 256, 0, stream>>>((const float4*)x, (char4*)qx, deqx);

    // GEMM1: [32768,1024] x [3072,1024]^T -> hidden bf16 (relu^2 fused)
    // grid: 256 m-tiles x 12 n-tiles = 3072 blocks
    gemm_i8<1024, 12, true, __hip_bfloat16><<<3072, 256, 0, stream>>>(
        qx, 1024, qw_up, 1024, hidden, 3072, deqx, &sums[0], up_b);
    // quantize hidden rows in place (int8 overlaid, pitch 6144 B)
    hquant_k<<<32768, 384, 0, stream>>>((unsigned short*)hidden, deqh);
    // GEMM2: [32768,3072] x [1024,3072]^T -> d_out fp32
    // grid: 256 m-tiles x 4 n-tiles = 1024 blocks
    gemm_i8<3072, 4, false, float><<<1024, 256, 0, stream>>>(
        (const int8_t*)hidden, 6144, qw_dn, 3072, (float*)d_out, 1024,
        deqh, &sums[1], down_b);
}